// Round 7
// baseline (63.623 us; speedup 1.0000x reference)
//
#include <hip/hip_runtime.h>

#define DEV __device__ __forceinline__

// Truncated level-3 signature state: s1[4], s2[16] (i*4+j), s3[64] (i*16+j*4+k).

// s <- s (x) exp(dx). 176 VALU ops.
// n3[ijk] = s3 + s2[ij]*dx[k] + (s1[i] + dx[i]/3) * (dx[j]*dx[k]/2)
// n2[ij]  = s2 + (s1[i] + dx[i]/2) * dx[j]
DEV void sig_step(float s1[4], float s2[16], float s3[64], const float dx[4]) {
    float w[16], u[4], g[4];
#pragma unroll
    for (int j = 0; j < 4; ++j) {
        float hj = 0.5f * dx[j];
        g[j] = s1[j] + hj;
        u[j] = fmaf(dx[j], (1.0f / 3.0f), s1[j]);
#pragma unroll
        for (int k = 0; k < 4; ++k) w[j * 4 + k] = hj * dx[k];
    }
#pragma unroll
    for (int i = 0; i < 4; ++i)
#pragma unroll
        for (int j = 0; j < 4; ++j)
#pragma unroll
            for (int k = 0; k < 4; ++k) {
                float v = s3[i * 16 + j * 4 + k];
                v = fmaf(s2[i * 4 + j], dx[k], v);
                v = fmaf(u[i], w[j * 4 + k], v);
                s3[i * 16 + j * 4 + k] = v;
            }
#pragma unroll
    for (int i = 0; i < 4; ++i)
#pragma unroll
        for (int j = 0; j < 4; ++j)
            s2[i * 4 + j] = fmaf(g[i], dx[j], s2[i * 4 + j]);
#pragma unroll
    for (int i = 0; i < 4; ++i) s1[i] += dx[i];
}

// s = exp(dx)  (first increment of a chunk)
DEV void sig_init(float s1[4], float s2[16], float s3[64], const float dx[4]) {
#pragma unroll
    for (int i = 0; i < 4; ++i) s1[i] = dx[i];
#pragma unroll
    for (int j = 0; j < 4; ++j) {
        float hj = 0.5f * dx[j];
#pragma unroll
        for (int k = 0; k < 4; ++k) s2[j * 4 + k] = hj * dx[k];
    }
#pragma unroll
    for (int i = 0; i < 4; ++i) {
        float ti = dx[i] * (1.0f / 3.0f);
#pragma unroll
        for (int jk = 0; jk < 16; ++jk) s3[i * 16 + jk] = ti * s2[jk];
    }
}

// a <- a (x) b, b read with stride 64 floats/term (works for LDS or global).
DEV void chen_fold(float a1[4], float a2[16], float a3[64], const float* __restrict__ b) {
    float b1[4], b2[16];
#pragma unroll
    for (int k = 0; k < 4; ++k) b1[k] = b[k * 64];
#pragma unroll
    for (int t = 0; t < 16; ++t) b2[t] = b[(4 + t) * 64];
#pragma unroll
    for (int i = 0; i < 4; ++i)
#pragma unroll
        for (int j = 0; j < 4; ++j)
#pragma unroll
            for (int k = 0; k < 4; ++k) {
                float v = a3[i * 16 + j * 4 + k] + b[(20 + i * 16 + j * 4 + k) * 64];
                v = fmaf(a2[i * 4 + j], b1[k], v);
                v = fmaf(a1[i], b2[j * 4 + k], v);
                a3[i * 16 + j * 4 + k] = v;
            }
#pragma unroll
    for (int i = 0; i < 4; ++i)
#pragma unroll
        for (int j = 0; j < 4; ++j)
            a2[i * 4 + j] = fmaf(a1[i], b1[j], a2[i * 4 + j] + b2[i * 4 + j]);
#pragma unroll
    for (int i = 0; i < 4; ++i) a1[i] += b1[i];
}

DEV void store_sig(float* dst, const float s1[4], const float s2[16], const float s3[64]) {
#pragma unroll
    for (int t = 0; t < 4; ++t) dst[t * 64] = s1[t];
#pragma unroll
    for (int t = 0; t < 16; ++t) dst[(4 + t) * 64] = s2[t];
#pragma unroll
    for (int t = 0; t < 64; ++t) dst[(20 + t) * 64] = s3[t];
}

DEV void load_sig(const float* src, float s1[4], float s2[16], float s3[64]) {
#pragma unroll
    for (int t = 0; t < 4; ++t) s1[t] = src[t * 64];
#pragma unroll
    for (int t = 0; t < 16; ++t) s2[t] = src[(4 + t) * 64];
#pragma unroll
    for (int t = 0; t < 64; ++t) s3[t] = src[(20 + t) * 64];
}

DEV void write_out(float* ob, const float s1[4], const float s2[16], const float s3[64]) {
#pragma unroll
    for (int t = 0; t < 4; ++t) ob[t] = s1[t];
#pragma unroll
    for (int t = 0; t < 16; ++t) ob[4 + t] = s2[t];
#pragma unroll
    for (int t = 0; t < 64; ++t) ob[20 + t] = s3[t];
}

// Geometry: B=64, T=1024, E=64, D=4.
// half_kernel: block (256 thr = 4 waves) per (b, half-piece h=0..15). Wave w
// BULK-LOADS its entire 16-frame chunk c = 4h+w into named registers (17
// compile-time-distinct loads, no rotating buffer -> compiler emits counted
// vmcnt waits, not per-step vmcnt(0) drains), then runs 15 pure-VALU steps.
// Then the block tree-folds the 4 chunk sigs in LDS -> half-piece signature.
// waves_per_eu(2,2) pins a 256-VGPR budget (frames 68 + state 84 + temps fits).
__global__ __attribute__((amdgpu_flat_work_group_size(256, 256),
                          amdgpu_waves_per_eu(2, 2)))
void half_kernel(const float* __restrict__ x, float* __restrict__ hsig,
                 float* __restrict__ bdxh) {
    __shared__ float sigbuf[2][84][64];
    __shared__ float bdxs[4][4][64];
    const int b = blockIdx.x >> 4;
    const int h = blockIdx.x & 15;
    const int w = threadIdx.x >> 6;
    const int e = threadIdx.x & 63;
    const int c = h * 4 + w;          // 16-frame chunk index 0..63
    // frame f of this chunk lives at xp[f * 64]
    const float4* xp = reinterpret_cast<const float4*>(x)
                     + (long)b * 65536 + (long)c * 16 * 64 + e;

    // bulk register staging: all frames, compile-time distinct addresses
    float4 f0  = xp[0 * 64],  f1  = xp[1 * 64],  f2  = xp[2 * 64],  f3  = xp[3 * 64];
    float4 f4  = xp[4 * 64],  f5  = xp[5 * 64],  f6  = xp[6 * 64],  f7  = xp[7 * 64];
    float4 f8  = xp[8 * 64],  f9  = xp[9 * 64],  f10 = xp[10 * 64], f11 = xp[11 * 64];
    float4 f12 = xp[12 * 64], f13 = xp[13 * 64], f14 = xp[14 * 64], f15 = xp[15 * 64];

    if (c > 0) {  // boundary increment: last frame of chunk c-1 -> first of c
        float4 pm = xp[-64];
        float bx[4] = {f0.x - pm.x, f0.y - pm.y, f0.z - pm.z, f0.w - pm.w};
        if (w > 0) {
#pragma unroll
            for (int jj = 0; jj < 4; ++jj) bdxs[w][jj][e] = bx[jj];
        } else {  // half-piece boundary (h>0): export for tree_kernel
            float* bb = &bdxh[(((long)(b * 16 + h)) * 4) * 64 + e];
#pragma unroll
            for (int jj = 0; jj < 4; ++jj) bb[jj * 64] = bx[jj];
        }
    }

    float s1[4], s2[16], s3[64];
#define DX_(a, bfr) { dxx[0] = bfr.x - a.x; dxx[1] = bfr.y - a.y; \
                      dxx[2] = bfr.z - a.z; dxx[3] = bfr.w - a.w; }
    float dxx[4];
    DX_(f0, f1);  sig_init(s1, s2, s3, dxx);
    DX_(f1, f2);  sig_step(s1, s2, s3, dxx);
    DX_(f2, f3);  sig_step(s1, s2, s3, dxx);
    DX_(f3, f4);  sig_step(s1, s2, s3, dxx);
    DX_(f4, f5);  sig_step(s1, s2, s3, dxx);
    DX_(f5, f6);  sig_step(s1, s2, s3, dxx);
    DX_(f6, f7);  sig_step(s1, s2, s3, dxx);
    DX_(f7, f8);  sig_step(s1, s2, s3, dxx);
    DX_(f8, f9);  sig_step(s1, s2, s3, dxx);
    DX_(f9, f10); sig_step(s1, s2, s3, dxx);
    DX_(f10, f11); sig_step(s1, s2, s3, dxx);
    DX_(f11, f12); sig_step(s1, s2, s3, dxx);
    DX_(f12, f13); sig_step(s1, s2, s3, dxx);
    DX_(f13, f14); sig_step(s1, s2, s3, dxx);
    DX_(f14, f15); sig_step(s1, s2, s3, dxx);
#undef DX_

    // round 1: waves 1,3 publish; waves 0,2 fold (join via boundary dx)
    if (w == 1 || w == 3) store_sig(&sigbuf[w >> 1][0][e], s1, s2, s3);
    __syncthreads();
    if (w == 0 || w == 2) {
        float dxl[4] = {bdxs[w + 1][0][e], bdxs[w + 1][1][e], bdxs[w + 1][2][e], bdxs[w + 1][3][e]};
        sig_step(s1, s2, s3, dxl);
        chen_fold(s1, s2, s3, &sigbuf[w >> 1][0][e]);
    }
    __syncthreads();
    // round 2: wave 2 publishes; wave 0 folds -> half-piece signature
    if (w == 2) store_sig(&sigbuf[0][0][e], s1, s2, s3);
    __syncthreads();
    if (w == 0) {
        float dxl[4] = {bdxs[2][0][e], bdxs[2][1][e], bdxs[2][2][e], bdxs[2][3][e]};
        sig_step(s1, s2, s3, dxl);
        chen_fold(s1, s2, s3, &sigbuf[0][0][e]);
        store_sig(&hsig[(((long)(b * 16 + h)) * 84) * 64 + e], s1, s2, s3);
    }
}

// tree_kernel: one block (8 waves = 512 thr) per b. r0: wave w folds halves
// (2w,2w+1) -> piece w -> pg7+w. r1: even waves -> pg3..6. r2: w0,w4 -> pg1,pg2.
// r3: w0 -> pg0. All 15 outputs written here.
__global__ __attribute__((amdgpu_flat_work_group_size(512, 512),
                          amdgpu_waves_per_eu(2, 2)))
void tree_kernel(const float* __restrict__ hsig, const float* __restrict__ bdxh,
                 float* __restrict__ out) {
    __shared__ float sigbuf[4][84][64];
    const int b = blockIdx.x;
    const int w = threadIdx.x >> 6;   // 0..7
    const int e = threadIdx.x & 63;

    float s1[4], s2[16], s3[64];
    // r0: piece w = hsig[2w] (x) exp(bdxh[2w+1]) (x) hsig[2w+1]  -> pg 7+w
    load_sig(&hsig[(((long)(b * 16 + 2 * w)) * 84) * 64 + e], s1, s2, s3);
    {
        const float* bb = &bdxh[(((long)(b * 16 + 2 * w + 1)) * 4) * 64 + e];
        float dx[4] = {bb[0], bb[64], bb[128], bb[192]};
        sig_step(s1, s2, s3, dx);
        chen_fold(s1, s2, s3, &hsig[(((long)(b * 16 + 2 * w + 1)) * 84) * 64 + e]);
    }
    write_out(&out[(((long)(b * 64 + e)) * 15 + 7 + w) * 84], s1, s2, s3);

    // odd waves publish pieces 1,3,5,7 -> sigbuf[0..3]
    if (w & 1) store_sig(&sigbuf[w >> 1][0][e], s1, s2, s3);
    __syncthreads();
    // r1: even wave w folds piece w with piece w+1 (boundary h = 2w+2) -> pg 3+w/2
    if (!(w & 1)) {
        const float* bb = &bdxh[(((long)(b * 16 + 2 * w + 2)) * 4) * 64 + e];
        float dx[4] = {bb[0], bb[64], bb[128], bb[192]};
        sig_step(s1, s2, s3, dx);
        chen_fold(s1, s2, s3, &sigbuf[w >> 1][0][e]);
        write_out(&out[(((long)(b * 64 + e)) * 15 + 3 + (w >> 1)) * 84], s1, s2, s3);
    }
    __syncthreads();
    // waves 2,6 publish quarters 1,3
    if (w == 2) store_sig(&sigbuf[0][0][e], s1, s2, s3);
    if (w == 6) store_sig(&sigbuf[1][0][e], s1, s2, s3);
    __syncthreads();
    // r2: w0: quarter0 (x) exp(h=4) (x) quarter1 -> pg1; w4: (h=12) -> pg2
    if (w == 0 || w == 4) {
        const int hh = (w == 0) ? 4 : 12;
        const float* bb = &bdxh[(((long)(b * 16 + hh)) * 4) * 64 + e];
        float dx[4] = {bb[0], bb[64], bb[128], bb[192]};
        sig_step(s1, s2, s3, dx);
        chen_fold(s1, s2, s3, &sigbuf[(w == 0) ? 0 : 1][0][e]);
        write_out(&out[(((long)(b * 64 + e)) * 15 + 1 + (w >> 2)) * 84], s1, s2, s3);
    }
    __syncthreads();
    // w4 publishes half1
    if (w == 4) store_sig(&sigbuf[2][0][e], s1, s2, s3);
    __syncthreads();
    // r3: w0: half0 (x) exp(h=8) (x) half1 -> pg0
    if (w == 0) {
        const float* bb = &bdxh[(((long)(b * 16 + 8)) * 4) * 64 + e];
        float dx[4] = {bb[0], bb[64], bb[128], bb[192]};
        sig_step(s1, s2, s3, dx);
        chen_fold(s1, s2, s3, &sigbuf[2][0][e]);
        write_out(&out[(((long)(b * 64 + e)) * 15 + 0) * 84], s1, s2, s3);
    }
}

// Fallback: direct sequential scan per (b, piece) — only if ws is too small.
__global__ __attribute__((amdgpu_flat_work_group_size(64, 64),
                          amdgpu_waves_per_eu(1, 1)))
void direct_kernel(const float* __restrict__ x, float* __restrict__ out) {
    const int pg = blockIdx.x % 15;
    const int b = blockIdx.x / 15;
    const int e = threadIdx.x;
    int lvl, p;
    if (pg == 0)      { lvl = 0; p = 0; }
    else if (pg < 3)  { lvl = 1; p = pg - 1; }
    else if (pg < 7)  { lvl = 2; p = pg - 3; }
    else              { lvl = 3; p = pg - 7; }
    const int L = 1024 >> lvl;
    const int t0 = p * L;
    const float4* xf = reinterpret_cast<const float4*>(x);
    const long base = (long)b * 65536;

    float4 prev = xf[base + (long)t0 * 64 + e];
    float s1[4], s2[16], s3[64];
    {
        float4 cur = xf[base + (long)(t0 + 1) * 64 + e];
        float dx[4] = {cur.x - prev.x, cur.y - prev.y, cur.z - prev.z, cur.w - prev.w};
        sig_init(s1, s2, s3, dx);
        prev = cur;
    }
    for (int i = 2; i < L; ++i) {
        float4 cur = xf[base + (long)(t0 + i) * 64 + e];
        float dx[4] = {cur.x - prev.x, cur.y - prev.y, cur.z - prev.z, cur.w - prev.w};
        prev = cur;
        sig_step(s1, s2, s3, dx);
    }
    write_out(&out[(((long)(b * 64 + e)) * 15 + pg) * 84], s1, s2, s3);
}

extern "C" void kernel_launch(void* const* d_in, const int* in_sizes, int n_in,
                              void* d_out, int out_size, void* d_ws, size_t ws_size,
                              hipStream_t stream) {
    (void)in_sizes; (void)n_in; (void)out_size;
    const float* x = (const float*)d_in[0];
    float* out = (float*)d_out;

    const size_t h_elems = (size_t)64 * 16 * 84 * 64;
    const size_t bdx_elems = (size_t)64 * 16 * 4 * 64;
    const size_t need = (h_elems + bdx_elems) * sizeof(float);

    if (ws_size >= need) {
        float* hsig = (float*)d_ws;
        float* bdxh = hsig + h_elems;
        half_kernel<<<64 * 16, 256, 0, stream>>>(x, hsig, bdxh);
        tree_kernel<<<64, 512, 0, stream>>>(hsig, bdxh, out);
    } else {
        direct_kernel<<<64 * 15, 64, 0, stream>>>(x, out);
    }
}

// Round 8
// 53.996 us; speedup vs baseline: 1.1783x; 1.1783x over previous
//
#include <hip/hip_runtime.h>

#define DEV __device__ __forceinline__

// Truncated level-3 signature state: s1[4], s2[16] (i*4+j), s3[64] (i*16+j*4+k).

// s <- s (x) exp(dx). 176 VALU ops.
// n3[ijk] = s3 + s2[ij]*dx[k] + (s1[i] + dx[i]/3) * (dx[j]*dx[k]/2)
// n2[ij]  = s2 + (s1[i] + dx[i]/2) * dx[j]
DEV void sig_step(float s1[4], float s2[16], float s3[64], const float dx[4]) {
    float w[16], u[4], g[4];
#pragma unroll
    for (int j = 0; j < 4; ++j) {
        float hj = 0.5f * dx[j];
        g[j] = s1[j] + hj;
        u[j] = fmaf(dx[j], (1.0f / 3.0f), s1[j]);
#pragma unroll
        for (int k = 0; k < 4; ++k) w[j * 4 + k] = hj * dx[k];
    }
#pragma unroll
    for (int i = 0; i < 4; ++i)
#pragma unroll
        for (int j = 0; j < 4; ++j)
#pragma unroll
            for (int k = 0; k < 4; ++k) {
                float v = s3[i * 16 + j * 4 + k];
                v = fmaf(s2[i * 4 + j], dx[k], v);
                v = fmaf(u[i], w[j * 4 + k], v);
                s3[i * 16 + j * 4 + k] = v;
            }
#pragma unroll
    for (int i = 0; i < 4; ++i)
#pragma unroll
        for (int j = 0; j < 4; ++j)
            s2[i * 4 + j] = fmaf(g[i], dx[j], s2[i * 4 + j]);
#pragma unroll
    for (int i = 0; i < 4; ++i) s1[i] += dx[i];
}

// s = exp(dx)  (first increment of a chunk)
DEV void sig_init(float s1[4], float s2[16], float s3[64], const float dx[4]) {
#pragma unroll
    for (int i = 0; i < 4; ++i) s1[i] = dx[i];
#pragma unroll
    for (int j = 0; j < 4; ++j) {
        float hj = 0.5f * dx[j];
#pragma unroll
        for (int k = 0; k < 4; ++k) s2[j * 4 + k] = hj * dx[k];
    }
#pragma unroll
    for (int i = 0; i < 4; ++i) {
        float ti = dx[i] * (1.0f / 3.0f);
#pragma unroll
        for (int jk = 0; jk < 16; ++jk) s3[i * 16 + jk] = ti * s2[jk];
    }
}

// a <- a (x) b, b read with stride 64 floats/term (works for LDS or global).
DEV void chen_fold(float a1[4], float a2[16], float a3[64], const float* __restrict__ b) {
    float b1[4], b2[16];
#pragma unroll
    for (int k = 0; k < 4; ++k) b1[k] = b[k * 64];
#pragma unroll
    for (int t = 0; t < 16; ++t) b2[t] = b[(4 + t) * 64];
#pragma unroll
    for (int i = 0; i < 4; ++i)
#pragma unroll
        for (int j = 0; j < 4; ++j)
#pragma unroll
            for (int k = 0; k < 4; ++k) {
                float v = a3[i * 16 + j * 4 + k] + b[(20 + i * 16 + j * 4 + k) * 64];
                v = fmaf(a2[i * 4 + j], b1[k], v);
                v = fmaf(a1[i], b2[j * 4 + k], v);
                a3[i * 16 + j * 4 + k] = v;
            }
#pragma unroll
    for (int i = 0; i < 4; ++i)
#pragma unroll
        for (int j = 0; j < 4; ++j)
            a2[i * 4 + j] = fmaf(a1[i], b1[j], a2[i * 4 + j] + b2[i * 4 + j]);
#pragma unroll
    for (int i = 0; i < 4; ++i) a1[i] += b1[i];
}

DEV void store_sig(float* dst, const float s1[4], const float s2[16], const float s3[64]) {
#pragma unroll
    for (int t = 0; t < 4; ++t) dst[t * 64] = s1[t];
#pragma unroll
    for (int t = 0; t < 16; ++t) dst[(4 + t) * 64] = s2[t];
#pragma unroll
    for (int t = 0; t < 64; ++t) dst[(20 + t) * 64] = s3[t];
}

DEV void load_sig(const float* src, float s1[4], float s2[16], float s3[64]) {
#pragma unroll
    for (int t = 0; t < 4; ++t) s1[t] = src[t * 64];
#pragma unroll
    for (int t = 0; t < 16; ++t) s2[t] = src[(4 + t) * 64];
#pragma unroll
    for (int t = 0; t < 64; ++t) s3[t] = src[(20 + t) * 64];
}

DEV void write_out(float* ob, const float s1[4], const float s2[16], const float s3[64]) {
#pragma unroll
    for (int t = 0; t < 4; ++t) ob[t] = s1[t];
#pragma unroll
    for (int t = 0; t < 16; ++t) ob[4 + t] = s2[t];
#pragma unroll
    for (int t = 0; t < 64; ++t) ob[20 + t] = s3[t];
}

// Geometry: B=64, T=1024, E=64, D=4.
// half_kernel: block (256 thr = 4 waves) per (b, half-piece h=0..15), covering
// frames h*64..h*64+63. Phase 1: reg-stage the 64 frames into a 64 KiB LDS
// buffer (load->ds_write, short live ranges -> no VGPR spill; R7 showed the
// allocator caps at 128 VGPRs and spills long-lived staged frames to scratch).
// Phase 2: wave w scans increments from LDS (w<3: frames 16w..16w+16, 16 inc;
// w3: 48..63, 15 inc). Waves share endpoint frames -> intra-block joins are
// plain Chen products (no boundary sig_step). Phase 3: tree-fold in LDS
// (sig slots alias the dead frame buffer). Scan-phase regs: 84 state + ~38.
__global__ __attribute__((amdgpu_flat_work_group_size(256, 256),
                          amdgpu_waves_per_eu(2)))
void half_kernel(const float* __restrict__ x, float* __restrict__ hsig,
                 float* __restrict__ bdxh) {
    __shared__ float lds[16384];          // 64 KiB: frames, then aliased sig slots
    float4* lf = reinterpret_cast<float4*>(lds);       // lf[f*64 + e] = frame f, lane e
    const int b = blockIdx.x >> 4;
    const int h = blockIdx.x & 15;
    const int w = threadIdx.x >> 6;
    const int e = threadIdx.x & 63;
    const float4* xg4 = reinterpret_cast<const float4*>(x) + (long)b * 65536;
    const int fbase = h * 64;             // first frame of this half-piece

    // ---- Phase 1: stage 16 frames per wave into LDS ----
#pragma unroll
    for (int k = 0; k < 16; ++k) {
        const int f = w * 16 + k;
        float4 v = xg4[(long)(fbase + f) * 64 + e];
        lf[f * 64 + e] = v;
    }
    // half-piece boundary increment export (h>0): frame fbase-1 -> fbase
    if (w == 0 && h > 0) {
        float4 pm = xg4[(long)(fbase - 1) * 64 + e];
        float4 p0 = xg4[(long)fbase * 64 + e];   // L1/L2 hit (just loaded)
        float* bb = &bdxh[(((long)(b * 16 + h)) * 4) * 64 + e];
        bb[0]   = p0.x - pm.x;
        bb[64]  = p0.y - pm.y;
        bb[128] = p0.z - pm.z;
        bb[192] = p0.w - pm.w;
    }
    __syncthreads();

    // ---- Phase 2: scan from LDS ----
    const int base = w * 16;
    const int NI = (w < 3) ? 16 : 15;     // increments this wave
    float s1[4], s2[16], s3[64];
    float dxx[4];
#define DX_(a, c) { dxx[0] = c.x - a.x; dxx[1] = c.y - a.y; \
                    dxx[2] = c.z - a.z; dxx[3] = c.w - a.w; }
    float4 a = lf[base * 64 + e];
    float4 nx = lf[(base + 1) * 64 + e];
    DX_(a, nx); sig_init(s1, s2, s3, dxx);
    a = nx;
    nx = lf[(base + 2) * 64 + e];         // 1-ahead prefetch from LDS
#pragma unroll 1
    for (int j = 2; j <= NI; ++j) {
        float4 cu = nx;
        int jn = j + 1; jn = jn > NI ? NI : jn;
        nx = lf[(base + jn) * 64 + e];
        DX_(a, cu); sig_step(s1, s2, s3, dxx);
        a = cu;
    }
#undef DX_
    __syncthreads();                      // all frame reads done; frames now dead

    // ---- Phase 3: fold (sig slots alias the frame buffer) ----
    float* slot0 = &lds[0];               // 84*64 floats = 21 KiB
    float* slot1 = &lds[84 * 64];
    if (w == 1) store_sig(slot0 + e, s1, s2, s3);
    if (w == 3) store_sig(slot1 + e, s1, s2, s3);
    __syncthreads();
    if (w == 0) chen_fold(s1, s2, s3, slot0 + e);   // S0 (x) S1
    if (w == 2) chen_fold(s1, s2, s3, slot1 + e);   // S2 (x) S3
    __syncthreads();
    if (w == 2) store_sig(slot0 + e, s1, s2, s3);
    __syncthreads();
    if (w == 0) {
        chen_fold(s1, s2, s3, slot0 + e);           // half-piece signature
        store_sig(&hsig[(((long)(b * 16 + h)) * 84) * 64 + e], s1, s2, s3);
    }
}

// tree_kernel: one block (8 waves = 512 thr) per b. r0: wave w folds halves
// (2w,2w+1) -> piece w -> pg7+w. r1: even waves -> pg3..6. r2: w0,w4 -> pg1,pg2.
// r3: w0 -> pg0. All 15 outputs written here.
__global__ __attribute__((amdgpu_flat_work_group_size(512, 512),
                          amdgpu_waves_per_eu(2)))
void tree_kernel(const float* __restrict__ hsig, const float* __restrict__ bdxh,
                 float* __restrict__ out) {
    __shared__ float sigbuf[4][84][64];
    const int b = blockIdx.x;
    const int w = threadIdx.x >> 6;   // 0..7
    const int e = threadIdx.x & 63;

    float s1[4], s2[16], s3[64];
    // r0: piece w = hsig[2w] (x) exp(bdxh[2w+1]) (x) hsig[2w+1]  -> pg 7+w
    load_sig(&hsig[(((long)(b * 16 + 2 * w)) * 84) * 64 + e], s1, s2, s3);
    {
        const float* bb = &bdxh[(((long)(b * 16 + 2 * w + 1)) * 4) * 64 + e];
        float dx[4] = {bb[0], bb[64], bb[128], bb[192]};
        sig_step(s1, s2, s3, dx);
        chen_fold(s1, s2, s3, &hsig[(((long)(b * 16 + 2 * w + 1)) * 84) * 64 + e]);
    }
    write_out(&out[(((long)(b * 64 + e)) * 15 + 7 + w) * 84], s1, s2, s3);

    // odd waves publish pieces 1,3,5,7 -> sigbuf[0..3]
    if (w & 1) store_sig(&sigbuf[w >> 1][0][e], s1, s2, s3);
    __syncthreads();
    // r1: even wave w folds piece w with piece w+1 (boundary h = 2w+2) -> pg 3+w/2
    if (!(w & 1)) {
        const float* bb = &bdxh[(((long)(b * 16 + 2 * w + 2)) * 4) * 64 + e];
        float dx[4] = {bb[0], bb[64], bb[128], bb[192]};
        sig_step(s1, s2, s3, dx);
        chen_fold(s1, s2, s3, &sigbuf[w >> 1][0][e]);
        write_out(&out[(((long)(b * 64 + e)) * 15 + 3 + (w >> 1)) * 84], s1, s2, s3);
    }
    __syncthreads();
    // waves 2,6 publish quarters 1,3
    if (w == 2) store_sig(&sigbuf[0][0][e], s1, s2, s3);
    if (w == 6) store_sig(&sigbuf[1][0][e], s1, s2, s3);
    __syncthreads();
    // r2: w0: quarter0 (x) exp(h=4) (x) quarter1 -> pg1; w4: (h=12) -> pg2
    if (w == 0 || w == 4) {
        const int hh = (w == 0) ? 4 : 12;
        const float* bb = &bdxh[(((long)(b * 16 + hh)) * 4) * 64 + e];
        float dx[4] = {bb[0], bb[64], bb[128], bb[192]};
        sig_step(s1, s2, s3, dx);
        chen_fold(s1, s2, s3, &sigbuf[(w == 0) ? 0 : 1][0][e]);
        write_out(&out[(((long)(b * 64 + e)) * 15 + 1 + (w >> 2)) * 84], s1, s2, s3);
    }
    __syncthreads();
    // w4 publishes half1
    if (w == 4) store_sig(&sigbuf[2][0][e], s1, s2, s3);
    __syncthreads();
    // r3: w0: half0 (x) exp(h=8) (x) half1 -> pg0
    if (w == 0) {
        const float* bb = &bdxh[(((long)(b * 16 + 8)) * 4) * 64 + e];
        float dx[4] = {bb[0], bb[64], bb[128], bb[192]};
        sig_step(s1, s2, s3, dx);
        chen_fold(s1, s2, s3, &sigbuf[2][0][e]);
        write_out(&out[(((long)(b * 64 + e)) * 15 + 0) * 84], s1, s2, s3);
    }
}

// Fallback: direct sequential scan per (b, piece) — only if ws is too small.
__global__ __attribute__((amdgpu_flat_work_group_size(64, 64),
                          amdgpu_waves_per_eu(1)))
void direct_kernel(const float* __restrict__ x, float* __restrict__ out) {
    const int pg = blockIdx.x % 15;
    const int b = blockIdx.x / 15;
    const int e = threadIdx.x;
    int lvl, p;
    if (pg == 0)      { lvl = 0; p = 0; }
    else if (pg < 3)  { lvl = 1; p = pg - 1; }
    else if (pg < 7)  { lvl = 2; p = pg - 3; }
    else              { lvl = 3; p = pg - 7; }
    const int L = 1024 >> lvl;
    const int t0 = p * L;
    const float4* xf = reinterpret_cast<const float4*>(x);
    const long base = (long)b * 65536;

    float4 prev = xf[base + (long)t0 * 64 + e];
    float s1[4], s2[16], s3[64];
    {
        float4 cur = xf[base + (long)(t0 + 1) * 64 + e];
        float dx[4] = {cur.x - prev.x, cur.y - prev.y, cur.z - prev.z, cur.w - prev.w};
        sig_init(s1, s2, s3, dx);
        prev = cur;
    }
    for (int i = 2; i < L; ++i) {
        float4 cur = xf[base + (long)(t0 + i) * 64 + e];
        float dx[4] = {cur.x - prev.x, cur.y - prev.y, cur.z - prev.z, cur.w - prev.w};
        prev = cur;
        sig_step(s1, s2, s3, dx);
    }
    write_out(&out[(((long)(b * 64 + e)) * 15 + pg) * 84], s1, s2, s3);
}

extern "C" void kernel_launch(void* const* d_in, const int* in_sizes, int n_in,
                              void* d_out, int out_size, void* d_ws, size_t ws_size,
                              hipStream_t stream) {
    (void)in_sizes; (void)n_in; (void)out_size;
    const float* x = (const float*)d_in[0];
    float* out = (float*)d_out;

    const size_t h_elems = (size_t)64 * 16 * 84 * 64;
    const size_t bdx_elems = (size_t)64 * 16 * 4 * 64;
    const size_t need = (h_elems + bdx_elems) * sizeof(float);

    if (ws_size >= need) {
        float* hsig = (float*)d_ws;
        float* bdxh = hsig + h_elems;
        half_kernel<<<64 * 16, 256, 0, stream>>>(x, hsig, bdxh);
        tree_kernel<<<64, 512, 0, stream>>>(hsig, bdxh, out);
    } else {
        direct_kernel<<<64 * 15, 64, 0, stream>>>(x, out);
    }
}

// Round 9
// 48.367 us; speedup vs baseline: 1.3154x; 1.1164x over previous
//
#include <hip/hip_runtime.h>

#define DEV __device__ __forceinline__

// Truncated level-3 signature state: s1[4], s2[16] (i*4+j), s3[64] (i*16+j*4+k).

// Async global->LDS, 16B per lane. LDS dest is wave-uniform base + lane*16.
DEV void async_stage16(const void* gsrc, void* ldst) {
    __builtin_amdgcn_global_load_lds(
        (const __attribute__((address_space(1))) unsigned int*)gsrc,
        (__attribute__((address_space(3))) unsigned int*)ldst, 16, 0, 0);
}

// s <- s (x) exp(dx). 112 VALU ops (factored):
//   h_j = dx_j/2; u_i = s1_i + dx_i/3; g_i = s1_i + h_i
//   t_ij = s2_ij + u_i*h_j          (old s2!)
//   s3[ijk] += t_ij * dx_k          (= s2 dx + 0.5 s1 dx dx + dx^3/6)
//   s2[ij]  += g_i * dx_j
//   s1      += dx
DEV void sig_step(float s1[4], float s2[16], float s3[64], const float dx[4]) {
    float h[4], u[4], g[4];
#pragma unroll
    for (int j = 0; j < 4; ++j) {
        h[j] = 0.5f * dx[j];
        u[j] = fmaf(dx[j], (1.0f / 3.0f), s1[j]);
        g[j] = s1[j] + h[j];
    }
#pragma unroll
    for (int i = 0; i < 4; ++i)
#pragma unroll
        for (int j = 0; j < 4; ++j) {
            float t = fmaf(u[i], h[j], s2[i * 4 + j]);
#pragma unroll
            for (int k = 0; k < 4; ++k)
                s3[i * 16 + j * 4 + k] = fmaf(t, dx[k], s3[i * 16 + j * 4 + k]);
        }
#pragma unroll
    for (int i = 0; i < 4; ++i)
#pragma unroll
        for (int j = 0; j < 4; ++j)
            s2[i * 4 + j] = fmaf(g[i], dx[j], s2[i * 4 + j]);
#pragma unroll
    for (int i = 0; i < 4; ++i) s1[i] += dx[i];
}

// s = exp(dx)
DEV void sig_init(float s1[4], float s2[16], float s3[64], const float dx[4]) {
#pragma unroll
    for (int i = 0; i < 4; ++i) s1[i] = dx[i];
#pragma unroll
    for (int j = 0; j < 4; ++j) {
        float hj = 0.5f * dx[j];
#pragma unroll
        for (int k = 0; k < 4; ++k) s2[j * 4 + k] = hj * dx[k];
    }
#pragma unroll
    for (int i = 0; i < 4; ++i) {
        float ti = dx[i] * (1.0f / 3.0f);
#pragma unroll
        for (int jk = 0; jk < 16; ++jk) s3[i * 16 + jk] = ti * s2[jk];
    }
}

// a <- a (x) b, b read with stride 64 floats/term (LDS or global).
DEV void chen_fold(float a1[4], float a2[16], float a3[64], const float* __restrict__ b) {
    float b1[4], b2[16];
#pragma unroll
    for (int k = 0; k < 4; ++k) b1[k] = b[k * 64];
#pragma unroll
    for (int t = 0; t < 16; ++t) b2[t] = b[(4 + t) * 64];
#pragma unroll
    for (int i = 0; i < 4; ++i)
#pragma unroll
        for (int j = 0; j < 4; ++j)
#pragma unroll
            for (int k = 0; k < 4; ++k) {
                float v = a3[i * 16 + j * 4 + k] + b[(20 + i * 16 + j * 4 + k) * 64];
                v = fmaf(a2[i * 4 + j], b1[k], v);
                v = fmaf(a1[i], b2[j * 4 + k], v);
                a3[i * 16 + j * 4 + k] = v;
            }
#pragma unroll
    for (int i = 0; i < 4; ++i)
#pragma unroll
        for (int j = 0; j < 4; ++j)
            a2[i * 4 + j] = fmaf(a1[i], b1[j], a2[i * 4 + j] + b2[i * 4 + j]);
#pragma unroll
    for (int i = 0; i < 4; ++i) a1[i] += b1[i];
}

DEV void store_sig(float* dst, const float s1[4], const float s2[16], const float s3[64]) {
#pragma unroll
    for (int t = 0; t < 4; ++t) dst[t * 64] = s1[t];
#pragma unroll
    for (int t = 0; t < 16; ++t) dst[(4 + t) * 64] = s2[t];
#pragma unroll
    for (int t = 0; t < 64; ++t) dst[(20 + t) * 64] = s3[t];
}

DEV void load_sig(const float* src, float s1[4], float s2[16], float s3[64]) {
#pragma unroll
    for (int t = 0; t < 4; ++t) s1[t] = src[t * 64];
#pragma unroll
    for (int t = 0; t < 16; ++t) s2[t] = src[(4 + t) * 64];
#pragma unroll
    for (int t = 0; t < 64; ++t) s3[t] = src[(20 + t) * 64];
}

DEV void write_out(float* ob, const float s1[4], const float s2[16], const float s3[64]) {
#pragma unroll
    for (int t = 0; t < 4; ++t) ob[t] = s1[t];
#pragma unroll
    for (int t = 0; t < 16; ++t) ob[4 + t] = s2[t];
#pragma unroll
    for (int t = 0; t < 64; ++t) ob[20 + t] = s3[t];
}

// Geometry: B=64, T=1024, E=64, D=4.
// half_kernel: block (4 waves) per (b, half h=0..15), frames h*64..h*64+63.
// Phase 1: async global_load_lds staging (16 frames/wave, no VGPR use, one
// vmcnt drain). Phase 2: wave w scans from LDS (w<3: 16 inc, w3: 15 inc;
// waves share endpoint frames -> joins are plain Chen products). Phase 3:
// in-LDS tree fold (slots alias the dead frame buffer) -> hsig.
__global__ __attribute__((amdgpu_flat_work_group_size(256, 256),
                          amdgpu_waves_per_eu(2, 2)))
void half_kernel(const float* __restrict__ x, float* __restrict__ hsig,
                 float* __restrict__ bdxh) {
    __shared__ float lds[16384];          // 64 KiB
    float4* lf = reinterpret_cast<float4*>(lds);       // lf[f*64 + e]
    const int b = blockIdx.x >> 4;
    const int h = blockIdx.x & 15;
    const int w = threadIdx.x >> 6;
    const int e = threadIdx.x & 63;
    const float4* xg4 = reinterpret_cast<const float4*>(x) + (long)b * 65536;
    const int fbase = h * 64;

    // ---- Phase 1: async stage 16 frames per wave ----
#pragma unroll
    for (int k = 0; k < 16; ++k) {
        const int f = w * 16 + k;
        async_stage16(xg4 + (long)(fbase + f) * 64 + e, &lf[f * 64]);
    }
    // half boundary increment export (h>0): frame fbase-1 -> fbase
    if (w == 0 && h > 0) {
        float4 pm = xg4[(long)(fbase - 1) * 64 + e];
        float4 p0 = xg4[(long)fbase * 64 + e];
        float* bb = &bdxh[(((long)(b * 16 + h)) * 4) * 64 + e];
        bb[0]   = p0.x - pm.x;
        bb[64]  = p0.y - pm.y;
        bb[128] = p0.z - pm.z;
        bb[192] = p0.w - pm.w;
    }
    asm volatile("s_waitcnt vmcnt(0)" ::: "memory");
    __syncthreads();

    // ---- Phase 2: scan from LDS ----
    const int base = w * 16;
    const int NI = (w < 3) ? 16 : 15;
    float s1[4], s2[16], s3[64];
    float dxx[4];
#define DX_(a, c) { dxx[0] = c.x - a.x; dxx[1] = c.y - a.y; \
                    dxx[2] = c.z - a.z; dxx[3] = c.w - a.w; }
    float4 a = lf[base * 64 + e];
    float4 nx = lf[(base + 1) * 64 + e];
    DX_(a, nx); sig_init(s1, s2, s3, dxx);
    a = nx;
    nx = lf[(base + 2) * 64 + e];
#pragma unroll 1
    for (int j = 2; j <= NI; ++j) {
        float4 cu = nx;
        int jn = j + 1; jn = jn > NI ? NI : jn;
        nx = lf[(base + jn) * 64 + e];
        DX_(a, cu); sig_step(s1, s2, s3, dxx);
        a = cu;
    }
#undef DX_
    __syncthreads();                      // frames dead

    // ---- Phase 3: fold ----
    float* slot0 = &lds[0];
    float* slot1 = &lds[84 * 64];
    if (w == 1) store_sig(slot0 + e, s1, s2, s3);
    if (w == 3) store_sig(slot1 + e, s1, s2, s3);
    __syncthreads();
    if (w == 0) chen_fold(s1, s2, s3, slot0 + e);
    if (w == 2) chen_fold(s1, s2, s3, slot1 + e);
    __syncthreads();
    if (w == 2) store_sig(slot0 + e, s1, s2, s3);
    __syncthreads();
    if (w == 0) {
        chen_fold(s1, s2, s3, slot0 + e);
        store_sig(&hsig[(((long)(b * 16 + h)) * 84) * 64 + e], s1, s2, s3);
    }
}

// quad_kernel: block (2 waves) per (b, quarter q=0..3) over halves 4q..4q+3.
// Wave w joins halves (4q+2w, 4q+2w+1) -> piece p=2q+w -> out pg7+p. Then
// w0 joins the two pieces -> quarter -> out pg3+q and qsig.
__global__ __attribute__((amdgpu_flat_work_group_size(128, 128),
                          amdgpu_waves_per_eu(1, 1)))
void quad_kernel(const float* __restrict__ hsig, const float* __restrict__ bdxh,
                 float* __restrict__ qsig, float* __restrict__ out) {
    __shared__ float slot[84 * 64];
    const int b = blockIdx.x >> 2;
    const int q = blockIdx.x & 3;
    const int w = threadIdx.x >> 6;   // 0..1
    const int e = threadIdx.x & 63;
    const int h0 = q * 4 + w * 2;

    float s1[4], s2[16], s3[64];
    load_sig(&hsig[(((long)(b * 16 + h0)) * 84) * 64 + e], s1, s2, s3);
    {
        const float* bb = &bdxh[(((long)(b * 16 + h0 + 1)) * 4) * 64 + e];
        float dx[4] = {bb[0], bb[64], bb[128], bb[192]};
        sig_step(s1, s2, s3, dx);
        chen_fold(s1, s2, s3, &hsig[(((long)(b * 16 + h0 + 1)) * 84) * 64 + e]);
    }
    write_out(&out[(((long)(b * 64 + e)) * 15 + 7 + 2 * q + w) * 84], s1, s2, s3);

    if (w == 1) store_sig(&slot[e], s1, s2, s3);
    __syncthreads();
    if (w == 0) {
        const float* bb = &bdxh[(((long)(b * 16 + q * 4 + 2)) * 4) * 64 + e];
        float dx[4] = {bb[0], bb[64], bb[128], bb[192]};
        sig_step(s1, s2, s3, dx);
        chen_fold(s1, s2, s3, &slot[e]);
        store_sig(&qsig[(((long)(b * 4 + q)) * 84) * 64 + e], s1, s2, s3);
        write_out(&out[(((long)(b * 64 + e)) * 15 + 3 + q) * 84], s1, s2, s3);
    }
}

// final_kernel: block (2 waves) per b. w0: pg1 = q0 (x) q1 (boundary half 4);
// w1: pg2 = q2 (x) q3 (boundary half 12); then w0: pg0 = pg1 (x) pg2
// (boundary half 8).
__global__ __attribute__((amdgpu_flat_work_group_size(128, 128),
                          amdgpu_waves_per_eu(1, 1)))
void final_kernel(const float* __restrict__ qsig, const float* __restrict__ bdxh,
                  float* __restrict__ out) {
    __shared__ float slot[84 * 64];
    const int b = blockIdx.x;
    const int w = threadIdx.x >> 6;   // 0..1
    const int e = threadIdx.x & 63;

    float s1[4], s2[16], s3[64];
    const int q0 = w * 2;             // q0 or q2
    load_sig(&qsig[(((long)(b * 4 + q0)) * 84) * 64 + e], s1, s2, s3);
    {
        const int hb = (w == 0) ? 4 : 12;
        const float* bb = &bdxh[(((long)(b * 16 + hb)) * 4) * 64 + e];
        float dx[4] = {bb[0], bb[64], bb[128], bb[192]};
        sig_step(s1, s2, s3, dx);
        chen_fold(s1, s2, s3, &qsig[(((long)(b * 4 + q0 + 1)) * 84) * 64 + e]);
    }
    write_out(&out[(((long)(b * 64 + e)) * 15 + 1 + w) * 84], s1, s2, s3);

    if (w == 1) store_sig(&slot[e], s1, s2, s3);
    __syncthreads();
    if (w == 0) {
        const float* bb = &bdxh[(((long)(b * 16 + 8)) * 4) * 64 + e];
        float dx[4] = {bb[0], bb[64], bb[128], bb[192]};
        sig_step(s1, s2, s3, dx);
        chen_fold(s1, s2, s3, &slot[e]);
        write_out(&out[(((long)(b * 64 + e)) * 15 + 0) * 84], s1, s2, s3);
    }
}

// Fallback: direct sequential scan per (b, piece) — only if ws is too small.
__global__ __attribute__((amdgpu_flat_work_group_size(64, 64),
                          amdgpu_waves_per_eu(1, 1)))
void direct_kernel(const float* __restrict__ x, float* __restrict__ out) {
    const int pg = blockIdx.x % 15;
    const int b = blockIdx.x / 15;
    const int e = threadIdx.x;
    int lvl, p;
    if (pg == 0)      { lvl = 0; p = 0; }
    else if (pg < 3)  { lvl = 1; p = pg - 1; }
    else if (pg < 7)  { lvl = 2; p = pg - 3; }
    else              { lvl = 3; p = pg - 7; }
    const int L = 1024 >> lvl;
    const int t0 = p * L;
    const float4* xf = reinterpret_cast<const float4*>(x);
    const long base = (long)b * 65536;

    float4 prev = xf[base + (long)t0 * 64 + e];
    float s1[4], s2[16], s3[64];
    {
        float4 cur = xf[base + (long)(t0 + 1) * 64 + e];
        float dx[4] = {cur.x - prev.x, cur.y - prev.y, cur.z - prev.z, cur.w - prev.w};
        sig_init(s1, s2, s3, dx);
        prev = cur;
    }
    for (int i = 2; i < L; ++i) {
        float4 cur = xf[base + (long)(t0 + i) * 64 + e];
        float dx[4] = {cur.x - prev.x, cur.y - prev.y, cur.z - prev.z, cur.w - prev.w};
        prev = cur;
        sig_step(s1, s2, s3, dx);
    }
    write_out(&out[(((long)(b * 64 + e)) * 15 + pg) * 84], s1, s2, s3);
}

extern "C" void kernel_launch(void* const* d_in, const int* in_sizes, int n_in,
                              void* d_out, int out_size, void* d_ws, size_t ws_size,
                              hipStream_t stream) {
    (void)in_sizes; (void)n_in; (void)out_size;
    const float* x = (const float*)d_in[0];
    float* out = (float*)d_out;

    const size_t h_elems = (size_t)64 * 16 * 84 * 64;   // hsig
    const size_t b_elems = (size_t)64 * 16 * 4 * 64;    // bdxh
    const size_t q_elems = (size_t)64 * 4 * 84 * 64;    // qsig
    const size_t need = (h_elems + b_elems + q_elems) * sizeof(float);

    if (ws_size >= need) {
        float* hsig = (float*)d_ws;
        float* bdxh = hsig + h_elems;
        float* qsig = bdxh + b_elems;
        half_kernel<<<64 * 16, 256, 0, stream>>>(x, hsig, bdxh);
        quad_kernel<<<64 * 4, 128, 0, stream>>>(hsig, bdxh, qsig, out);
        final_kernel<<<64, 128, 0, stream>>>(qsig, bdxh, out);
    } else {
        direct_kernel<<<64 * 15, 64, 0, stream>>>(x, out);
    }
}

// Round 10
// 48.281 us; speedup vs baseline: 1.3178x; 1.0018x over previous
//
#include <hip/hip_runtime.h>

#define DEV __device__ __forceinline__

// Truncated level-3 signature state: s1[4], s2[16] (i*4+j), s3[64] (i*16+j*4+k).

// Async global->LDS, 16B per lane. LDS dest is wave-uniform base + lane*16.
DEV void async_stage16(const void* gsrc, void* ldst) {
    __builtin_amdgcn_global_load_lds(
        (const __attribute__((address_space(1))) unsigned int*)gsrc,
        (__attribute__((address_space(3))) unsigned int*)ldst, 16, 0, 0);
}

// s <- s (x) exp(dx). ~112 VALU ops (factored):
//   h_j = dx_j/2; u_i = s1_i + dx_i/3; g_i = s1_i + h_i
//   t_ij = s2_ij + u_i*h_j  (old s2);  s3[ijk] += t_ij*dx_k
//   s2[ij] += g_i*dx_j;  s1 += dx
DEV void sig_step(float s1[4], float s2[16], float s3[64], const float dx[4]) {
    float h[4], u[4], g[4];
#pragma unroll
    for (int j = 0; j < 4; ++j) {
        h[j] = 0.5f * dx[j];
        u[j] = fmaf(dx[j], (1.0f / 3.0f), s1[j]);
        g[j] = s1[j] + h[j];
    }
#pragma unroll
    for (int i = 0; i < 4; ++i)
#pragma unroll
        for (int j = 0; j < 4; ++j) {
            float t = fmaf(u[i], h[j], s2[i * 4 + j]);
#pragma unroll
            for (int k = 0; k < 4; ++k)
                s3[i * 16 + j * 4 + k] = fmaf(t, dx[k], s3[i * 16 + j * 4 + k]);
        }
#pragma unroll
    for (int i = 0; i < 4; ++i)
#pragma unroll
        for (int j = 0; j < 4; ++j)
            s2[i * 4 + j] = fmaf(g[i], dx[j], s2[i * 4 + j]);
#pragma unroll
    for (int i = 0; i < 4; ++i) s1[i] += dx[i];
}

// s = exp(dx)
DEV void sig_init(float s1[4], float s2[16], float s3[64], const float dx[4]) {
#pragma unroll
    for (int i = 0; i < 4; ++i) s1[i] = dx[i];
#pragma unroll
    for (int j = 0; j < 4; ++j) {
        float hj = 0.5f * dx[j];
#pragma unroll
        for (int k = 0; k < 4; ++k) s2[j * 4 + k] = hj * dx[k];
    }
#pragma unroll
    for (int i = 0; i < 4; ++i) {
        float ti = dx[i] * (1.0f / 3.0f);
#pragma unroll
        for (int jk = 0; jk < 16; ++jk) s3[i * 16 + jk] = ti * s2[jk];
    }
}

// a <- a (x) b, b read with stride 64 floats/term (LDS or global).
DEV void chen_fold(float a1[4], float a2[16], float a3[64], const float* __restrict__ b) {
    float b1[4], b2[16];
#pragma unroll
    for (int k = 0; k < 4; ++k) b1[k] = b[k * 64];
#pragma unroll
    for (int t = 0; t < 16; ++t) b2[t] = b[(4 + t) * 64];
#pragma unroll
    for (int i = 0; i < 4; ++i)
#pragma unroll
        for (int j = 0; j < 4; ++j)
#pragma unroll
            for (int k = 0; k < 4; ++k) {
                float v = a3[i * 16 + j * 4 + k] + b[(20 + i * 16 + j * 4 + k) * 64];
                v = fmaf(a2[i * 4 + j], b1[k], v);
                v = fmaf(a1[i], b2[j * 4 + k], v);
                a3[i * 16 + j * 4 + k] = v;
            }
#pragma unroll
    for (int i = 0; i < 4; ++i)
#pragma unroll
        for (int j = 0; j < 4; ++j)
            a2[i * 4 + j] = fmaf(a1[i], b1[j], a2[i * 4 + j] + b2[i * 4 + j]);
#pragma unroll
    for (int i = 0; i < 4; ++i) a1[i] += b1[i];
}

DEV void store_sig(float* dst, const float s1[4], const float s2[16], const float s3[64]) {
#pragma unroll
    for (int t = 0; t < 4; ++t) dst[t * 64] = s1[t];
#pragma unroll
    for (int t = 0; t < 16; ++t) dst[(4 + t) * 64] = s2[t];
#pragma unroll
    for (int t = 0; t < 64; ++t) dst[(20 + t) * 64] = s3[t];
}

DEV void load_sig(const float* src, float s1[4], float s2[16], float s3[64]) {
#pragma unroll
    for (int t = 0; t < 4; ++t) s1[t] = src[t * 64];
#pragma unroll
    for (int t = 0; t < 16; ++t) s2[t] = src[(4 + t) * 64];
#pragma unroll
    for (int t = 0; t < 64; ++t) s3[t] = src[(20 + t) * 64];
}

// float4-packed output write: 21 stores instead of 84 scalar stores.
// ob is 16B-aligned (84 floats = 21 float4 per signature record).
DEV void write_out4(float* ob, const float s1[4], const float s2[16], const float s3[64]) {
    float4* o4 = reinterpret_cast<float4*>(ob);
    o4[0] = make_float4(s1[0], s1[1], s1[2], s1[3]);
#pragma unroll
    for (int t = 0; t < 4; ++t)
        o4[1 + t] = make_float4(s2[4 * t], s2[4 * t + 1], s2[4 * t + 2], s2[4 * t + 3]);
#pragma unroll
    for (int t = 0; t < 16; ++t)
        o4[5 + t] = make_float4(s3[4 * t], s3[4 * t + 1], s3[4 * t + 2], s3[4 * t + 3]);
}

// Geometry: B=64, T=1024, E=64, D=4.
// half_kernel: block (4 waves) per (b, half h=0..15), frames h*64..h*64+63.
// PER-WAVE pipeline (no pre-scan block barrier): wave w async-stages frames
// w*16 .. w*16+16 (17 frames; the shared endpoint frame is also staged by the
// next wave — identical-value write race, benign), waits vmcnt(0) for its OWN
// loads only, scans its 16 increments (w3: 16 frames, 15 inc) from LDS.
// Stage latency of one wave hides under another wave's scan. Then one block
// barrier, and an in-LDS tree fold (slots alias dead frames) -> hsig.
__global__ __launch_bounds__(256, 2)
void half_kernel(const float* __restrict__ x, float* __restrict__ hsig,
                 float* __restrict__ bdxh) {
    __shared__ float lds[16384];          // 64 KiB: 64 frames, aliased sig slots
    float4* lf = reinterpret_cast<float4*>(lds);       // lf[f*64 + e]
    const int b = blockIdx.x >> 4;
    const int h = blockIdx.x & 15;
    const int w = threadIdx.x >> 6;
    const int e = threadIdx.x & 63;
    const float4* xg4 = reinterpret_cast<const float4*>(x) + (long)b * 65536;
    const int fbase = h * 64;

    // ---- Phase 1: per-wave async stage (17 frames; w3: 16) ----
#pragma unroll
    for (int k = 0; k < 17; ++k) {
        if (k < 16 || w < 3) {
            const int f = w * 16 + k;
            async_stage16(xg4 + (long)(fbase + f) * 64 + e, &lf[f * 64]);
        }
    }
    // half boundary increment export (h>0): frame fbase-1 -> fbase
    if (w == 0 && h > 0) {
        float4 pm = xg4[(long)(fbase - 1) * 64 + e];
        float4 p0 = xg4[(long)fbase * 64 + e];
        float* bb = &bdxh[(((long)(b * 16 + h)) * 4) * 64 + e];
        bb[0]   = p0.x - pm.x;
        bb[64]  = p0.y - pm.y;
        bb[128] = p0.z - pm.z;
        bb[192] = p0.w - pm.w;
    }
    asm volatile("s_waitcnt vmcnt(0)" ::: "memory");   // own-wave loads only

    // ---- Phase 2: scan own chunk from LDS (no block barrier needed) ----
    const int base = w * 16;
    const int NI = (w < 3) ? 16 : 15;
    float s1[4], s2[16], s3[64];
    float dxx[4];
#define DX_(a, c) { dxx[0] = c.x - a.x; dxx[1] = c.y - a.y; \
                    dxx[2] = c.z - a.z; dxx[3] = c.w - a.w; }
    float4 a = lf[base * 64 + e];
    float4 nx = lf[(base + 1) * 64 + e];
    DX_(a, nx); sig_init(s1, s2, s3, dxx);
    a = nx;
    nx = lf[(base + 2) * 64 + e];
#pragma unroll 1
    for (int j = 2; j <= NI; ++j) {
        float4 cu = nx;
        int jn = j + 1; jn = jn > NI ? NI : jn;
        nx = lf[(base + jn) * 64 + e];
        DX_(a, cu); sig_step(s1, s2, s3, dxx);
        a = cu;
    }
#undef DX_
    __syncthreads();                      // all scans done; frames now dead

    // ---- Phase 3: fold (slots alias the dead frame buffer) ----
    float* slot0 = &lds[0];
    float* slot1 = &lds[84 * 64];
    if (w == 1) store_sig(slot0 + e, s1, s2, s3);
    if (w == 3) store_sig(slot1 + e, s1, s2, s3);
    __syncthreads();
    if (w == 0) chen_fold(s1, s2, s3, slot0 + e);      // S0 (x) S1
    if (w == 2) chen_fold(s1, s2, s3, slot1 + e);      // S2 (x) S3
    __syncthreads();
    if (w == 2) store_sig(slot0 + e, s1, s2, s3);
    __syncthreads();
    if (w == 0) {
        chen_fold(s1, s2, s3, slot0 + e);              // half-piece signature
        store_sig(&hsig[(((long)(b * 16 + h)) * 84) * 64 + e], s1, s2, s3);
    }
}

// quad_kernel: block (2 waves) per (b, quarter q=0..3) over halves 4q..4q+3.
// Wave w joins halves (4q+2w, 4q+2w+1) -> piece p=2q+w -> out pg7+p. Then
// w0 joins the two pieces -> quarter -> out pg3+q and qsig.
__global__ __launch_bounds__(128, 2)
void quad_kernel(const float* __restrict__ hsig, const float* __restrict__ bdxh,
                 float* __restrict__ qsig, float* __restrict__ out) {
    __shared__ float slot[84 * 64];
    const int b = blockIdx.x >> 2;
    const int q = blockIdx.x & 3;
    const int w = threadIdx.x >> 6;   // 0..1
    const int e = threadIdx.x & 63;
    const int h0 = q * 4 + w * 2;

    float s1[4], s2[16], s3[64];
    load_sig(&hsig[(((long)(b * 16 + h0)) * 84) * 64 + e], s1, s2, s3);
    {
        const float* bb = &bdxh[(((long)(b * 16 + h0 + 1)) * 4) * 64 + e];
        float dx[4] = {bb[0], bb[64], bb[128], bb[192]};
        sig_step(s1, s2, s3, dx);
        chen_fold(s1, s2, s3, &hsig[(((long)(b * 16 + h0 + 1)) * 84) * 64 + e]);
    }
    write_out4(&out[(((long)(b * 64 + e)) * 15 + 7 + 2 * q + w) * 84], s1, s2, s3);

    if (w == 1) store_sig(&slot[e], s1, s2, s3);
    __syncthreads();
    if (w == 0) {
        const float* bb = &bdxh[(((long)(b * 16 + q * 4 + 2)) * 4) * 64 + e];
        float dx[4] = {bb[0], bb[64], bb[128], bb[192]};
        sig_step(s1, s2, s3, dx);
        chen_fold(s1, s2, s3, &slot[e]);
        store_sig(&qsig[(((long)(b * 4 + q)) * 84) * 64 + e], s1, s2, s3);
        write_out4(&out[(((long)(b * 64 + e)) * 15 + 3 + q) * 84], s1, s2, s3);
    }
}

// final_kernel: block (2 waves) per b. w0: pg1 = q0 (x) q1 (boundary half 4);
// w1: pg2 = q2 (x) q3 (boundary half 12); then w0: pg0 = pg1 (x) pg2.
__global__ __launch_bounds__(128, 2)
void final_kernel(const float* __restrict__ qsig, const float* __restrict__ bdxh,
                  float* __restrict__ out) {
    __shared__ float slot[84 * 64];
    const int b = blockIdx.x;
    const int w = threadIdx.x >> 6;   // 0..1
    const int e = threadIdx.x & 63;

    float s1[4], s2[16], s3[64];
    const int q0 = w * 2;
    load_sig(&qsig[(((long)(b * 4 + q0)) * 84) * 64 + e], s1, s2, s3);
    {
        const int hb = (w == 0) ? 4 : 12;
        const float* bb = &bdxh[(((long)(b * 16 + hb)) * 4) * 64 + e];
        float dx[4] = {bb[0], bb[64], bb[128], bb[192]};
        sig_step(s1, s2, s3, dx);
        chen_fold(s1, s2, s3, &qsig[(((long)(b * 4 + q0 + 1)) * 84) * 64 + e]);
    }
    write_out4(&out[(((long)(b * 64 + e)) * 15 + 1 + w) * 84], s1, s2, s3);

    if (w == 1) store_sig(&slot[e], s1, s2, s3);
    __syncthreads();
    if (w == 0) {
        const float* bb = &bdxh[(((long)(b * 16 + 8)) * 4) * 64 + e];
        float dx[4] = {bb[0], bb[64], bb[128], bb[192]};
        sig_step(s1, s2, s3, dx);
        chen_fold(s1, s2, s3, &slot[e]);
        write_out4(&out[(((long)(b * 64 + e)) * 15 + 0) * 84], s1, s2, s3);
    }
}

// Fallback: direct sequential scan per (b, piece) — only if ws is too small.
__global__ __launch_bounds__(64, 1)
void direct_kernel(const float* __restrict__ x, float* __restrict__ out) {
    const int pg = blockIdx.x % 15;
    const int b = blockIdx.x / 15;
    const int e = threadIdx.x;
    int lvl, p;
    if (pg == 0)      { lvl = 0; p = 0; }
    else if (pg < 3)  { lvl = 1; p = pg - 1; }
    else if (pg < 7)  { lvl = 2; p = pg - 3; }
    else              { lvl = 3; p = pg - 7; }
    const int L = 1024 >> lvl;
    const int t0 = p * L;
    const float4* xf = reinterpret_cast<const float4*>(x);
    const long base = (long)b * 65536;

    float4 prev = xf[base + (long)t0 * 64 + e];
    float s1[4], s2[16], s3[64];
    {
        float4 cur = xf[base + (long)(t0 + 1) * 64 + e];
        float dx[4] = {cur.x - prev.x, cur.y - prev.y, cur.z - prev.z, cur.w - prev.w};
        sig_init(s1, s2, s3, dx);
        prev = cur;
    }
    for (int i = 2; i < L; ++i) {
        float4 cur = xf[base + (long)(t0 + i) * 64 + e];
        float dx[4] = {cur.x - prev.x, cur.y - prev.y, cur.z - prev.z, cur.w - prev.w};
        prev = cur;
        sig_step(s1, s2, s3, dx);
    }
    write_out4(&out[(((long)(b * 64 + e)) * 15 + pg) * 84], s1, s2, s3);
}

extern "C" void kernel_launch(void* const* d_in, const int* in_sizes, int n_in,
                              void* d_out, int out_size, void* d_ws, size_t ws_size,
                              hipStream_t stream) {
    (void)in_sizes; (void)n_in; (void)out_size;
    const float* x = (const float*)d_in[0];
    float* out = (float*)d_out;

    const size_t h_elems = (size_t)64 * 16 * 84 * 64;   // hsig
    const size_t b_elems = (size_t)64 * 16 * 4 * 64;    // bdxh
    const size_t q_elems = (size_t)64 * 4 * 84 * 64;    // qsig
    const size_t need = (h_elems + b_elems + q_elems) * sizeof(float);

    if (ws_size >= need) {
        float* hsig = (float*)d_ws;
        float* bdxh = hsig + h_elems;
        float* qsig = bdxh + b_elems;
        half_kernel<<<64 * 16, 256, 0, stream>>>(x, hsig, bdxh);
        quad_kernel<<<64 * 4, 128, 0, stream>>>(hsig, bdxh, qsig, out);
        final_kernel<<<64, 128, 0, stream>>>(qsig, bdxh, out);
    } else {
        direct_kernel<<<64 * 15, 64, 0, stream>>>(x, out);
    }
}